// Round 21
// baseline (80.331 us; speedup 1.0000x reference)
//
#include <hip/hip_runtime.h>

typedef float  f32x4  __attribute__((ext_vector_type(4)));
typedef short  short8 __attribute__((ext_vector_type(8)));
typedef unsigned short ushort_t;
typedef ushort_t us4   __attribute__((ext_vector_type(4)));

#define NCOARSE 1024
#define NFINE   4096

__device__ __forceinline__ ushort_t f2bf(float f){
  union { float f; unsigned u; } a; a.f = f;
  unsigned u = a.u;
  return (ushort_t)((u + 0x7fffu + ((u >> 16) & 1u)) >> 16);
}

__device__ __forceinline__ f32x4 splat4(float v){ f32x4 t = {v, v, v, v}; return t; }

// ---- pack BOTH weight matrices (bf16, MFMA-B-fragment order) in one launch.
__global__ void prep_w2(const float* __restrict__ W1, const float* __restrict__ W2,
                        ushort_t* __restrict__ W1p, ushort_t* __restrict__ W2p){
  int e = blockIdx.x * 256 + threadIdx.x;        // grid 640*256 = 163840 exactly
  const float* W; ushort_t* Wp; int idx;
  if (e < 98304){ W = W1; Wp = W1p; idx = e; }
  else          { W = W2; Wp = W2p; idx = e - 98304; }
  int j    = idx & 7;
  int lane = (idx >> 3) & 63;
  int g    = idx >> 9;        // kc*16 + nb
  int nb   = g & 15;
  int kc   = g >> 4;
  int k = kc * 32 + (lane >> 4) * 8 + j;
  int n = nb * 16 + (lane & 15);
  Wp[idx] = f2bf(W[k * 256 + n]);
}

#define LDW4(DST, WP, STEP)                                                   \
  { _Pragma("unroll")                                                         \
    for (int n_ = 0; n_ < 4; ++n_)                                            \
      DST[n_] = *(const short8*)((WP) +                                       \
          ((size_t)(((STEP) * 16 + wp * 4 + n_) * 64 + lane)) * 8); }

// ---- MERGED: kNN (this block's 32 rows) -> gather -> GEMM1(relu) -> GEMM2(relu)
// r20 champion + two exact micro-levers:
//  (1) x_skip loads hoisted to kernel entry (HBM latency hides under the scan);
//  (2) candp stores DOUBLED coords (2x,2y,2z,|c|^2): dot2 == rn(2*dot) bit-
//      exactly (x2 is exact & commutes with rn), so d = (sf+sc) - dot2 matches
//      the reference expansion-form bits while saving one mul per eval.
__global__ __launch_bounds__(256, 3)
void fp_fused(const float* __restrict__ pos, const float* __restrict__ pos_skip,
              const float* __restrict__ x, const float* __restrict__ x_skip,
              const ushort_t* __restrict__ W1p, const float* __restrict__ b1,
              const ushort_t* __restrict__ W2p, const float* __restrict__ b2,
              float* __restrict__ out){
  __shared__ __align__(16) ushort_t hbuf[32 * 384];   // 24KB: cand -> h1 -> h2
  char* h1b = (char*)hbuf;
  char* h2b = (char*)hbuf;
  f32x4* candp = (f32x4*)hbuf;                        // 8*129*16B = 16.5KB alias
  const int tid  = threadIdx.x;
  const int lb   = ((blockIdx.x & 7) << 8) + (blockIdx.x >> 3);  // bijective: 2048=8*256
  const int row0 = lb * 32;
  const int b    = lb >> 7;            // cloud id (128 blocks per cloud)
  const int wp   = tid >> 6;
  const int lane = tid & 63;
  const int lhi  = lane >> 4;
  const int llo  = lane & 15;
  const int r    = tid >> 3;           // row group (knn query AND gather row)
  const int sub  = tid & 7;            // chunk (knn) / column slice (gather)

  // ---- (1) hoisted x_skip loads: issue now, consume in phase 2
  f32x4 xs[4];
  {
    const f32x4* xsr = (const f32x4*)(x_skip + (size_t)(row0 + r) * 128);
    #pragma unroll
    for (int it = 0; it < 4; ++it) xs[it] = xsr[it * 8 + sub];
  }

  // ======== PHASE 1: kNN for rows row0..row0+31 (reference fp32 arithmetic) ====
  {
    const float* p = pos + (size_t)b * NCOARSE * 3;
    for (int c = tid; c < NCOARSE; c += 256){
      float xx = p[3*c], yy = p[3*c+1], zz = p[3*c+2];
      float sc = __fadd_rn(__fadd_rn(__fmul_rn(xx,xx), __fmul_rn(yy,yy)), __fmul_rn(zz,zz));
      f32x4 v = { xx + xx, yy + yy, zz + zz, sc };   // doubled coords (exact)
      candp[(c >> 7) * 129 + (c & 127)] = v;
    }
  }
  __syncthreads();

  float wn0, wn1, wn2;
  int   ig0, ig1, ig2;
  {
    const int m = row0 + r;
    const float* q = pos_skip + (size_t)m * 3;
    float qx = q[0], qy = q[1], qz = q[2];
    float sf = __fadd_rn(__fadd_rn(__fmul_rn(qx,qx), __fmul_rn(qy,qy)), __fmul_rn(qz,qz));

    float d0 = 1e30f, d1 = 1e30f, d2 = 1e30f;
    int   i0 = 0,     i1 = 0,     i2 = 0;
    const int gbase = sub * 128;
    #pragma unroll 4
    for (int i = 0; i < 128; ++i){
      f32x4 v = candp[sub * 129 + i];
      // dot2 = rn(rn(rn(qx*2x)+rn(qy*2y))+rn(qz*2z)) == rn(2*dot) bit-exactly
      float dot2 = __fadd_rn(__fadd_rn(__fmul_rn(qx, v.x), __fmul_rn(qy, v.y)),
                             __fmul_rn(qz, v.z));
      float d = __fsub_rn(__fadd_rn(sf, v.w), dot2);
      d = fmaxf(d, 0.0f);
      if (d < d2){
        int gi = gbase + i;
        if (d < d1){
          d2 = d1; i2 = i1;
          if (d < d0){ d1 = d0; i1 = i0; d0 = d; i0 = gi; }
          else       { d1 = d;  i1 = gi; }
        } else { d2 = d; i2 = gi; }
      }
    }

    // butterfly merge: all 8 lanes end with the identical top-3
    #pragma unroll
    for (int mlev = 1; mlev <= 4; mlev <<= 1){
      float e0 = __shfl_xor(d0, mlev), e1 = __shfl_xor(d1, mlev), e2 = __shfl_xor(d2, mlev);
      int   j0 = __shfl_xor(i0, mlev), j1 = __shfl_xor(i1, mlev), j2 = __shfl_xor(i2, mlev);
      #pragma unroll
      for (int s = 0; s < 3; ++s){
        float e = (s == 0) ? e0 : (s == 1) ? e1 : e2;
        int   j = (s == 0) ? j0 : (s == 1) ? j1 : j2;
        bool l2 = (e < d2) || (e == d2 && j < i2);
        if (l2){
          bool l1 = (e < d1) || (e == d1 && j < i1);
          if (l1){
            d2 = d1; i2 = i1;
            bool l0 = (e < d0) || (e == d0 && j < i0);
            if (l0){ d1 = d0; i1 = i0; d0 = e; i0 = j; }
            else   { d1 = e;  i1 = j; }
          } else { d2 = e; i2 = j; }
        }
      }
    }

    float w0 = 1.0f / fmaxf(d0, 1e-16f);
    float w1 = 1.0f / fmaxf(d1, 1e-16f);
    float w2 = 1.0f / fmaxf(d2, 1e-16f);
    float ws = __fadd_rn(__fadd_rn(w0, w1), w2);
    wn0 = w0 / ws; wn1 = w1 / ws; wn2 = w2 / ws;
    ig0 = b * NCOARSE + i0; ig1 = b * NCOARSE + i1; ig2 = b * NCOARSE + i2;
  }
  __syncthreads();    // cand reads done; h1 may overlay

  // ======== PHASE 2: gather-stage h1 (idx/weights already in registers) ====
  {
    const f32x4* x0 = (const f32x4*)(x + (size_t)ig0 * 256);
    const f32x4* x1 = (const f32x4*)(x + (size_t)ig1 * 256);
    const f32x4* x2 = (const f32x4*)(x + (size_t)ig2 * 256);
    #pragma unroll
    for (int it = 0; it < 8; ++it){
      int c4 = it * 8 + sub;
      f32x4 v = x0[c4] * wn0 + x1[c4] * wn1 + x2[c4] * wn2;
      int byte = (r * 768 + c4 * 8) ^ ((r & 7) << 4);
      us4 pk = { f2bf(v.x), f2bf(v.y), f2bf(v.z), f2bf(v.w) };
      *(us4*)(h1b + byte) = pk;
    }
    #pragma unroll
    for (int it = 0; it < 4; ++it){
      int c4 = it * 8 + sub;
      f32x4 v = xs[it];
      int byte = (r * 768 + 512 + c4 * 8) ^ ((r & 7) << 4);
      us4 pk = { f2bf(v.x), f2bf(v.y), f2bf(v.z), f2bf(v.w) };
      *(us4*)(h1b + byte) = pk;
    }
  }
  __syncthreads();

  // ======== GEMM1: (32x384)@(384x256) ====
  f32x4 acc[2][4];
  #pragma unroll
  for (int nbp = 0; nbp < 4; ++nbp){
    float bb = b1[wp * 64 + nbp * 16 + llo];
    #pragma unroll
    for (int mb = 0; mb < 2; ++mb) acc[mb][nbp] = splat4(bb);
  }
  {
    short8 wr[3][4];
    LDW4(wr[0], W1p, 0);
    LDW4(wr[1], W1p, 1);
    LDW4(wr[2], W1p, 2);
    #pragma unroll
    for (int kk = 0; kk < 12; ++kk){
      short8 af[2];
      #pragma unroll
      for (int mb = 0; mb < 2; ++mb){
        int rr = mb * 16 + llo;
        int byte = (rr * 768 + kk * 64 + lhi * 16) ^ ((rr & 7) << 4);
        af[mb] = *(const short8*)(h1b + byte);
      }
      #pragma unroll
      for (int mb = 0; mb < 2; ++mb)
        #pragma unroll
        for (int nbp = 0; nbp < 4; ++nbp)
          acc[mb][nbp] = __builtin_amdgcn_mfma_f32_16x16x32_bf16(
              af[mb], wr[kk % 3][nbp], acc[mb][nbp], 0, 0, 0);
      if (kk + 3 < 12) { LDW4(wr[kk % 3], W1p, kk + 3); }
    }
  }
  __syncthreads();   // all h1 reads done before h2 overlays the buffer

  // ---- relu -> bf16 -> h2 (swizzled, overlays h1)
  #pragma unroll
  for (int mb = 0; mb < 2; ++mb)
    #pragma unroll
    for (int nbp = 0; nbp < 4; ++nbp)
      #pragma unroll
      for (int rg = 0; rg < 4; ++rg){
        int rr  = mb * 16 + lhi * 4 + rg;
        int col = wp * 64 + nbp * 16 + llo;
        int byte = (rr * 512 + col * 2) ^ ((rr & 7) << 4);
        *(ushort_t*)(h2b + byte) = f2bf(fmaxf(acc[mb][nbp][rg], 0.0f));
      }
  __syncthreads();

  // ======== GEMM2: (32x256)@(256x256) ====
  f32x4 acc2[2][4];
  #pragma unroll
  for (int nbp = 0; nbp < 4; ++nbp){
    float bb = b2[wp * 64 + nbp * 16 + llo];
    #pragma unroll
    for (int mb = 0; mb < 2; ++mb) acc2[mb][nbp] = splat4(bb);
  }
  {
    short8 wr[3][4];
    LDW4(wr[0], W2p, 0);
    LDW4(wr[1], W2p, 1);
    LDW4(wr[2], W2p, 2);
    #pragma unroll
    for (int kk = 0; kk < 8; ++kk){
      short8 af[2];
      #pragma unroll
      for (int mb = 0; mb < 2; ++mb){
        int rr = mb * 16 + llo;
        int byte = (rr * 512 + kk * 64 + lhi * 16) ^ ((rr & 7) << 4);
        af[mb] = *(const short8*)(h2b + byte);
      }
      #pragma unroll
      for (int mb = 0; mb < 2; ++mb)
        #pragma unroll
        for (int nbp = 0; nbp < 4; ++nbp)
          acc2[mb][nbp] = __builtin_amdgcn_mfma_f32_16x16x32_bf16(
              af[mb], wr[kk % 3][nbp], acc2[mb][nbp], 0, 0, 0);
      if (kk + 3 < 8) { LDW4(wr[kk % 3], W2p, kk + 3); }
    }
  }

  // ---- relu -> fp32 out
  #pragma unroll
  for (int mb = 0; mb < 2; ++mb)
    #pragma unroll
    for (int nbp = 0; nbp < 4; ++nbp)
      #pragma unroll
      for (int rg = 0; rg < 4; ++rg){
        int row = row0 + mb * 16 + lhi * 4 + rg;
        int col = wp * 64 + nbp * 16 + llo;
        out[(size_t)row * 256 + col] = fmaxf(acc2[mb][nbp][rg], 0.0f);
      }
}

extern "C" void kernel_launch(void* const* d_in, const int* in_sizes, int n_in,
                              void* d_out, int out_size, void* d_ws, size_t ws_size,
                              hipStream_t stream){
  (void)in_sizes; (void)n_in; (void)out_size; (void)ws_size;
  const float* x        = (const float*)d_in[0];
  const float* pos      = (const float*)d_in[1];
  const float* x_skip   = (const float*)d_in[3];
  const float* pos_skip = (const float*)d_in[4];
  const float* W1 = (const float*)d_in[6];
  const float* b1 = (const float*)d_in[7];
  const float* W2 = (const float*)d_in[8];
  const float* b2 = (const float*)d_in[9];
  float* out = (float*)d_out;
  char* ws = (char*)d_ws;
  ushort_t* W1p = (ushort_t*)(ws);                 // 196608 B
  ushort_t* W2p = (ushort_t*)(ws + 196608);        // 131072 B

  hipLaunchKernelGGL(prep_w2, dim3(640), dim3(256), 0, stream, W1, W2, W1p, W2p);
  hipLaunchKernelGGL(fp_fused, dim3(2048), dim3(256), 0, stream,
                     pos, pos_skip, x, x_skip, W1p, b1, W2p, b2, out);
}

// Round 22
// 78.796 us; speedup vs baseline: 1.0195x; 1.0195x over previous
//
#include <hip/hip_runtime.h>

typedef float  f32x4  __attribute__((ext_vector_type(4)));
typedef short  short8 __attribute__((ext_vector_type(8)));
typedef unsigned short ushort_t;
typedef ushort_t us4   __attribute__((ext_vector_type(4)));

#define NCOARSE 1024
#define NFINE   4096

__device__ __forceinline__ ushort_t f2bf(float f){
  union { float f; unsigned u; } a; a.f = f;
  unsigned u = a.u;
  return (ushort_t)((u + 0x7fffu + ((u >> 16) & 1u)) >> 16);
}

__device__ __forceinline__ f32x4 splat4(float v){ f32x4 t = {v, v, v, v}; return t; }

// ---- pack BOTH weight matrices (bf16, MFMA-B-fragment order) in one launch.
__global__ void prep_w2(const float* __restrict__ W1, const float* __restrict__ W2,
                        ushort_t* __restrict__ W1p, ushort_t* __restrict__ W2p){
  int e = blockIdx.x * 256 + threadIdx.x;        // grid 640*256 = 163840 exactly
  const float* W; ushort_t* Wp; int idx;
  if (e < 98304){ W = W1; Wp = W1p; idx = e; }
  else          { W = W2; Wp = W2p; idx = e - 98304; }
  int j    = idx & 7;
  int lane = (idx >> 3) & 63;
  int g    = idx >> 9;        // kc*16 + nb
  int nb   = g & 15;
  int kc   = g >> 4;
  int k = kc * 32 + (lane >> 4) * 8 + j;
  int n = nb * 16 + (lane & 15);
  Wp[idx] = f2bf(W[k * 256 + n]);
}

#define LDW4(DST, WP, STEP)                                                   \
  { _Pragma("unroll")                                                         \
    for (int n_ = 0; n_ < 4; ++n_)                                            \
      DST[n_] = *(const short8*)((WP) +                                       \
          ((size_t)(((STEP) * 16 + wp * 4 + n_) * 64 + lane)) * 8); }

// ---- MERGED: kNN (this block's 32 rows) -> gather -> GEMM1(relu) -> GEMM2(relu)
// FINAL (r20 champion, measured 78.8us):
//  - kNN replicates the reference's fp32 arithmetic EXACTLY (expansion form,
//    no fma, strict-< insertion == top_k lowest-index tie-break); 8 lanes per
//    query, butterfly merge leaves identical top-3 in all 8 lanes.
//  - knn result never leaves registers (block tiling == GEMM row tiling).
//  - GEMMs: bf16 MFMA 16x16x32, A swizzled in LDS (XOR (r&7)<<4), W prepacked
//    in B-fragment order read direct from L2, 3-slot consume-then-refill ring.
//  - h2 overlays h1 (24KB LDS); single kernel, 2 dispatches total.
__global__ __launch_bounds__(256, 3)
void fp_fused(const float* __restrict__ pos, const float* __restrict__ pos_skip,
              const float* __restrict__ x, const float* __restrict__ x_skip,
              const ushort_t* __restrict__ W1p, const float* __restrict__ b1,
              const ushort_t* __restrict__ W2p, const float* __restrict__ b2,
              float* __restrict__ out){
  __shared__ __align__(16) ushort_t hbuf[32 * 384];   // 24KB: cand -> h1 -> h2
  char* h1b = (char*)hbuf;
  char* h2b = (char*)hbuf;
  f32x4* candp = (f32x4*)hbuf;                        // 8*129*16B = 16.5KB alias
  const int tid  = threadIdx.x;
  const int lb   = ((blockIdx.x & 7) << 8) + (blockIdx.x >> 3);  // bijective: 2048=8*256
  const int row0 = lb * 32;
  const int b    = lb >> 7;            // cloud id (128 blocks per cloud)
  const int wp   = tid >> 6;
  const int lane = tid & 63;
  const int lhi  = lane >> 4;
  const int llo  = lane & 15;
  const int r    = tid >> 3;           // row group (knn query AND gather row)
  const int sub  = tid & 7;            // chunk (knn) / column slice (gather)

  // ======== PHASE 1: kNN for rows row0..row0+31 (reference fp32 arithmetic) ====
  {
    const float* p = pos + (size_t)b * NCOARSE * 3;
    for (int c = tid; c < NCOARSE; c += 256){
      float xx = p[3*c], yy = p[3*c+1], zz = p[3*c+2];
      float sc = __fadd_rn(__fadd_rn(__fmul_rn(xx,xx), __fmul_rn(yy,yy)), __fmul_rn(zz,zz));
      f32x4 v = { xx, yy, zz, sc };
      candp[(c >> 7) * 129 + (c & 127)] = v;
    }
  }
  __syncthreads();

  float wn0, wn1, wn2;
  int   ig0, ig1, ig2;
  {
    const int m = row0 + r;
    const float* q = pos_skip + (size_t)m * 3;
    float qx = q[0], qy = q[1], qz = q[2];
    float sf = __fadd_rn(__fadd_rn(__fmul_rn(qx,qx), __fmul_rn(qy,qy)), __fmul_rn(qz,qz));

    float d0 = 1e30f, d1 = 1e30f, d2 = 1e30f;
    int   i0 = 0,     i1 = 0,     i2 = 0;
    const int gbase = sub * 128;
    #pragma unroll 4
    for (int i = 0; i < 128; ++i){
      f32x4 v = candp[sub * 129 + i];
      float dot = __fadd_rn(__fadd_rn(__fmul_rn(qx, v.x), __fmul_rn(qy, v.y)),
                            __fmul_rn(qz, v.z));
      float d = __fsub_rn(__fadd_rn(sf, v.w), __fmul_rn(2.0f, dot));
      d = fmaxf(d, 0.0f);
      if (d < d2){
        int gi = gbase + i;
        if (d < d1){
          d2 = d1; i2 = i1;
          if (d < d0){ d1 = d0; i1 = i0; d0 = d; i0 = gi; }
          else       { d1 = d;  i1 = gi; }
        } else { d2 = d; i2 = gi; }
      }
    }

    // butterfly merge: all 8 lanes end with the identical top-3
    #pragma unroll
    for (int mlev = 1; mlev <= 4; mlev <<= 1){
      float e0 = __shfl_xor(d0, mlev), e1 = __shfl_xor(d1, mlev), e2 = __shfl_xor(d2, mlev);
      int   j0 = __shfl_xor(i0, mlev), j1 = __shfl_xor(i1, mlev), j2 = __shfl_xor(i2, mlev);
      #pragma unroll
      for (int s = 0; s < 3; ++s){
        float e = (s == 0) ? e0 : (s == 1) ? e1 : e2;
        int   j = (s == 0) ? j0 : (s == 1) ? j1 : j2;
        bool l2 = (e < d2) || (e == d2 && j < i2);
        if (l2){
          bool l1 = (e < d1) || (e == d1 && j < i1);
          if (l1){
            d2 = d1; i2 = i1;
            bool l0 = (e < d0) || (e == d0 && j < i0);
            if (l0){ d1 = d0; i1 = i0; d0 = e; i0 = j; }
            else   { d1 = e;  i1 = j; }
          } else { d2 = e; i2 = j; }
        }
      }
    }

    float w0 = 1.0f / fmaxf(d0, 1e-16f);
    float w1 = 1.0f / fmaxf(d1, 1e-16f);
    float w2 = 1.0f / fmaxf(d2, 1e-16f);
    float ws = __fadd_rn(__fadd_rn(w0, w1), w2);
    wn0 = w0 / ws; wn1 = w1 / ws; wn2 = w2 / ws;
    ig0 = b * NCOARSE + i0; ig1 = b * NCOARSE + i1; ig2 = b * NCOARSE + i2;
  }
  __syncthreads();    // cand reads done; h1 may overlay

  // ======== PHASE 2: gather-stage h1 (idx/weights already in registers) ====
  {
    const int m = row0 + r;
    const f32x4* xsr = (const f32x4*)(x_skip + (size_t)m * 128);
    f32x4 xs[4];
    #pragma unroll
    for (int it = 0; it < 4; ++it) xs[it] = xsr[it * 8 + sub];
    const f32x4* x0 = (const f32x4*)(x + (size_t)ig0 * 256);
    const f32x4* x1 = (const f32x4*)(x + (size_t)ig1 * 256);
    const f32x4* x2 = (const f32x4*)(x + (size_t)ig2 * 256);
    #pragma unroll
    for (int it = 0; it < 8; ++it){
      int c4 = it * 8 + sub;
      f32x4 v = x0[c4] * wn0 + x1[c4] * wn1 + x2[c4] * wn2;
      int byte = (r * 768 + c4 * 8) ^ ((r & 7) << 4);
      us4 pk = { f2bf(v.x), f2bf(v.y), f2bf(v.z), f2bf(v.w) };
      *(us4*)(h1b + byte) = pk;
    }
    #pragma unroll
    for (int it = 0; it < 4; ++it){
      int c4 = it * 8 + sub;
      f32x4 v = xs[it];
      int byte = (r * 768 + 512 + c4 * 8) ^ ((r & 7) << 4);
      us4 pk = { f2bf(v.x), f2bf(v.y), f2bf(v.z), f2bf(v.w) };
      *(us4*)(h1b + byte) = pk;
    }
  }
  __syncthreads();

  // ======== GEMM1: (32x384)@(384x256) ====
  f32x4 acc[2][4];
  #pragma unroll
  for (int nbp = 0; nbp < 4; ++nbp){
    float bb = b1[wp * 64 + nbp * 16 + llo];
    #pragma unroll
    for (int mb = 0; mb < 2; ++mb) acc[mb][nbp] = splat4(bb);
  }
  {
    short8 wr[3][4];
    LDW4(wr[0], W1p, 0);
    LDW4(wr[1], W1p, 1);
    LDW4(wr[2], W1p, 2);
    #pragma unroll
    for (int kk = 0; kk < 12; ++kk){
      short8 af[2];
      #pragma unroll
      for (int mb = 0; mb < 2; ++mb){
        int rr = mb * 16 + llo;
        int byte = (rr * 768 + kk * 64 + lhi * 16) ^ ((rr & 7) << 4);
        af[mb] = *(const short8*)(h1b + byte);
      }
      #pragma unroll
      for (int mb = 0; mb < 2; ++mb)
        #pragma unroll
        for (int nbp = 0; nbp < 4; ++nbp)
          acc[mb][nbp] = __builtin_amdgcn_mfma_f32_16x16x32_bf16(
              af[mb], wr[kk % 3][nbp], acc[mb][nbp], 0, 0, 0);
      if (kk + 3 < 12) { LDW4(wr[kk % 3], W1p, kk + 3); }
    }
  }
  __syncthreads();   // all h1 reads done before h2 overlays the buffer

  // ---- relu -> bf16 -> h2 (swizzled, overlays h1)
  #pragma unroll
  for (int mb = 0; mb < 2; ++mb)
    #pragma unroll
    for (int nbp = 0; nbp < 4; ++nbp)
      #pragma unroll
      for (int rg = 0; rg < 4; ++rg){
        int rr  = mb * 16 + lhi * 4 + rg;
        int col = wp * 64 + nbp * 16 + llo;
        int byte = (rr * 512 + col * 2) ^ ((rr & 7) << 4);
        *(ushort_t*)(h2b + byte) = f2bf(fmaxf(acc[mb][nbp][rg], 0.0f));
      }
  __syncthreads();

  // ======== GEMM2: (32x256)@(256x256) ====
  f32x4 acc2[2][4];
  #pragma unroll
  for (int nbp = 0; nbp < 4; ++nbp){
    float bb = b2[wp * 64 + nbp * 16 + llo];
    #pragma unroll
    for (int mb = 0; mb < 2; ++mb) acc2[mb][nbp] = splat4(bb);
  }
  {
    short8 wr[3][4];
    LDW4(wr[0], W2p, 0);
    LDW4(wr[1], W2p, 1);
    LDW4(wr[2], W2p, 2);
    #pragma unroll
    for (int kk = 0; kk < 8; ++kk){
      short8 af[2];
      #pragma unroll
      for (int mb = 0; mb < 2; ++mb){
        int rr = mb * 16 + llo;
        int byte = (rr * 512 + kk * 64 + lhi * 16) ^ ((rr & 7) << 4);
        af[mb] = *(const short8*)(h2b + byte);
      }
      #pragma unroll
      for (int mb = 0; mb < 2; ++mb)
        #pragma unroll
        for (int nbp = 0; nbp < 4; ++nbp)
          acc2[mb][nbp] = __builtin_amdgcn_mfma_f32_16x16x32_bf16(
              af[mb], wr[kk % 3][nbp], acc2[mb][nbp], 0, 0, 0);
      if (kk + 3 < 8) { LDW4(wr[kk % 3], W2p, kk + 3); }
    }
  }

  // ---- relu -> fp32 out
  #pragma unroll
  for (int mb = 0; mb < 2; ++mb)
    #pragma unroll
    for (int nbp = 0; nbp < 4; ++nbp)
      #pragma unroll
      for (int rg = 0; rg < 4; ++rg){
        int row = row0 + mb * 16 + lhi * 4 + rg;
        int col = wp * 64 + nbp * 16 + llo;
        out[(size_t)row * 256 + col] = fmaxf(acc2[mb][nbp][rg], 0.0f);
      }
}

extern "C" void kernel_launch(void* const* d_in, const int* in_sizes, int n_in,
                              void* d_out, int out_size, void* d_ws, size_t ws_size,
                              hipStream_t stream){
  (void)in_sizes; (void)n_in; (void)out_size; (void)ws_size;
  const float* x        = (const float*)d_in[0];
  const float* pos      = (const float*)d_in[1];
  const float* x_skip   = (const float*)d_in[3];
  const float* pos_skip = (const float*)d_in[4];
  const float* W1 = (const float*)d_in[6];
  const float* b1 = (const float*)d_in[7];
  const float* W2 = (const float*)d_in[8];
  const float* b2 = (const float*)d_in[9];
  float* out = (float*)d_out;
  char* ws = (char*)d_ws;
  ushort_t* W1p = (ushort_t*)(ws);                 // 196608 B
  ushort_t* W2p = (ushort_t*)(ws + 196608);        // 131072 B

  hipLaunchKernelGGL(prep_w2, dim3(640), dim3(256), 0, stream, W1, W2, W1p, W2p);
  hipLaunchKernelGGL(fp_fused, dim3(2048), dim3(256), 0, stream,
                     pos, pos_skip, x, x_skip, W1p, b1, W2p, b2, out);
}